// Round 2
// baseline (631.674 us; speedup 1.0000x reference)
//
#include <hip/hip_runtime.h>
#include <stdint.h>

#define B_    8
#define T_    4096
#define DIN   1024
#define HCH   1024
#define DOUT  1024
#define M_    (B_*T_)      // 32768 rows
#define CL    64           // scan chunk length
#define NCH   (T_/CL)      // 64 chunks
#define BK    64           // GEMM K-step

typedef unsigned short u16;
typedef __attribute__((ext_vector_type(8))) __bf16 bf16x8;
typedef __attribute__((ext_vector_type(4))) float  f32x4;

static __device__ __forceinline__ u16 f2bf(float f){
  unsigned u = __builtin_bit_cast(unsigned, f);
  return (u16)((u + 0x7FFFu + ((u >> 16) & 1u)) >> 16);   // RNE
}
static __device__ __forceinline__ float bf2f(u16 h){
  return __builtin_bit_cast(float, ((unsigned)h) << 16);
}

#define GLOAD_LDS16(gp, lp) __builtin_amdgcn_global_load_lds( \
    (__attribute__((address_space(1))) void*)(gp),            \
    (__attribute__((address_space(3))) void*)(lp), 16, 0, 0)

// ---------------- conversions ----------------
__global__ void cvt_bf16_kernel(const float* __restrict__ in, u16* __restrict__ out, int n4){
  int i = blockIdx.x * blockDim.x + threadIdx.x;
  if (i >= n4) return;
  float4 v = ((const float4*)in)[i];
  ushort4 o;
  o.x = f2bf(v.x); o.y = f2bf(v.y); o.z = f2bf(v.z); o.w = f2bf(v.w);
  ((ushort4*)out)[i] = o;
}

// in: R x C fp32 row-major  ->  out: C x R bf16 row-major
__global__ void transpose_cvt_kernel(const float* __restrict__ in, u16* __restrict__ out,
                                     int R, int C){
  __shared__ float tile[32][33];
  int tx = threadIdx.x & 31, ty = threadIdx.x >> 5;   // 32 x 8
  int c0 = blockIdx.x * 32, r0 = blockIdx.y * 32;
  #pragma unroll
  for (int j = 0; j < 4; ++j)
    tile[ty + j*8][tx] = in[(size_t)(r0 + ty + j*8) * C + c0 + tx];
  __syncthreads();
  #pragma unroll
  for (int j = 0; j < 4; ++j)
    out[(size_t)(c0 + ty + j*8) * R + r0 + tx] = f2bf(tile[tx][ty + j*8]);
}

// Detect is_init storage: 1 => byte-per-flag (bool/int8), 0 => int32 values 0/1.
__global__ void detect_kernel(const unsigned char* __restrict__ p, int* __restrict__ flag){
  __shared__ int s;
  if (threadIdx.x == 0) s = 0;
  __syncthreads();
  int f = 0;
  for (int i = threadIdx.x; i < B_*T_; i += 256)
    if ((i & 3) && p[i]) f = 1;
  if (f) atomicOr(&s, 1);
  __syncthreads();
  if (threadIdx.x == 0) *flag = s;
}

// ---------------- GEMM1: dual-tile (hidden+gate) + fused c,v epilogue ----------------
// A: xbf [M_][DIN] bf16.  BT: W_hg^T [2*HCH][DIN] bf16 (rows 0..1023 hidden, 1024.. gate)
__global__ __launch_bounds__(256, 2) void gemm1_kernel(
    const u16* __restrict__ A, const u16* __restrict__ BT,
    u16* __restrict__ cbuf, u16* __restrict__ vbuf)
{
  __shared__ u16 As[128*BK];
  __shared__ u16 Bh[128*BK];
  __shared__ u16 Bg[128*BK];
  int tid = threadIdx.x;
  int lane = tid & 63, w = tid >> 6;
  int wr = w >> 1, wc = w & 1;
  int lr = lane & 15, lg = lane >> 4;
  int m0 = blockIdx.x * 128, n0 = blockIdx.y * 128;

  f32x4 zf = {0.f, 0.f, 0.f, 0.f};
  f32x4 acch[4][4], accg[4][4];
  #pragma unroll
  for (int i = 0; i < 4; ++i)
    #pragma unroll
    for (int j = 0; j < 4; ++j){ acch[i][j] = zf; accg[i][j] = zf; }

  for (int k0 = 0; k0 < DIN; k0 += BK){
    __syncthreads();                       // prior tile's ds_reads done before overwrite
    #pragma unroll
    for (int i = 0; i < 4; ++i){
      int eo  = tid*8 + i*2048;            // element offset within 128x64 tile
      int row = eo >> 6, col = eo & 63;
      GLOAD_LDS16(A  + (size_t)(m0 + row)*DIN + k0 + col,        As + i*2048 + w*512);
      GLOAD_LDS16(BT + (size_t)(n0 + row)*DIN + k0 + col,        Bh + i*2048 + w*512);
      GLOAD_LDS16(BT + (size_t)(1024 + n0 + row)*DIN + k0 + col, Bg + i*2048 + w*512);
    }
    __syncthreads();                       // compiler drains vmcnt(0) here (m97 structure)
    #pragma unroll
    for (int ks = 0; ks < 2; ++ks){
      bf16x8 af[4], bh[4], bg[4];
      #pragma unroll
      for (int m = 0; m < 4; ++m)
        af[m] = *(const bf16x8*)&As[(wr*64 + m*16 + lr)*BK + ks*32 + lg*8];
      #pragma unroll
      for (int n = 0; n < 4; ++n){
        bh[n] = *(const bf16x8*)&Bh[(wc*64 + n*16 + lr)*BK + ks*32 + lg*8];
        bg[n] = *(const bf16x8*)&Bg[(wc*64 + n*16 + lr)*BK + ks*32 + lg*8];
      }
      #pragma unroll
      for (int m = 0; m < 4; ++m)
        #pragma unroll
        for (int n = 0; n < 4; ++n){
          acch[m][n] = __builtin_amdgcn_mfma_f32_16x16x32_bf16(af[m], bh[n], acch[m][n], 0, 0, 0);
          accg[m][n] = __builtin_amdgcn_mfma_f32_16x16x32_bf16(af[m], bg[n], accg[m][n], 0, 0, 0);
        }
    }
  }
  // epilogue: c = sigmoid(-gate), v = sigmoid(gate)*g(hidden)
  #pragma unroll
  for (int m = 0; m < 4; ++m)
    #pragma unroll
    for (int n = 0; n < 4; ++n)
      #pragma unroll
      for (int r = 0; r < 4; ++r){
        int row = m0 + wr*64 + m*16 + lg*4 + r;    // C/D: row=(lane>>4)*4+reg
        int col = n0 + wc*64 + n*16 + lr;          //      col=lane&15
        float hv = acch[m][n][r];
        float gv = accg[m][n][r];
        float c  = 1.f / (1.f + __expf(gv));
        float z  = 1.f / (1.f + __expf(-gv));
        float g  = (hv >= 0.f) ? (hv + 0.5f) : (1.f / (1.f + __expf(-hv)));
        size_t idx = (size_t)row * HCH + col;
        cbuf[idx] = f2bf(c);
        vbuf[idx] = f2bf(z * g);
      }
}

// ---------------- GEMM2: out = h @ W_out (fp32 out) ----------------
__global__ __launch_bounds__(256, 2) void gemm2_kernel(
    const u16* __restrict__ A, const u16* __restrict__ BT, float* __restrict__ out)
{
  __shared__ u16 As[128*BK];
  __shared__ u16 Bs[128*BK];
  int tid = threadIdx.x;
  int lane = tid & 63, w = tid >> 6;
  int wr = w >> 1, wc = w & 1;
  int lr = lane & 15, lg = lane >> 4;
  int m0 = blockIdx.x * 128, n0 = blockIdx.y * 128;

  f32x4 zf = {0.f, 0.f, 0.f, 0.f};
  f32x4 acc[4][4];
  #pragma unroll
  for (int i = 0; i < 4; ++i)
    #pragma unroll
    for (int j = 0; j < 4; ++j) acc[i][j] = zf;

  for (int k0 = 0; k0 < HCH; k0 += BK){
    __syncthreads();
    #pragma unroll
    for (int i = 0; i < 4; ++i){
      int eo  = tid*8 + i*2048;
      int row = eo >> 6, col = eo & 63;
      GLOAD_LDS16(A  + (size_t)(m0 + row)*HCH + k0 + col, As + i*2048 + w*512);
      GLOAD_LDS16(BT + (size_t)(n0 + row)*HCH + k0 + col, Bs + i*2048 + w*512);
    }
    __syncthreads();
    #pragma unroll
    for (int ks = 0; ks < 2; ++ks){
      bf16x8 af[4], bb[4];
      #pragma unroll
      for (int m = 0; m < 4; ++m)
        af[m] = *(const bf16x8*)&As[(wr*64 + m*16 + lr)*BK + ks*32 + lg*8];
      #pragma unroll
      for (int n = 0; n < 4; ++n)
        bb[n] = *(const bf16x8*)&Bs[(wc*64 + n*16 + lr)*BK + ks*32 + lg*8];
      #pragma unroll
      for (int m = 0; m < 4; ++m)
        #pragma unroll
        for (int n = 0; n < 4; ++n)
          acc[m][n] = __builtin_amdgcn_mfma_f32_16x16x32_bf16(af[m], bb[n], acc[m][n], 0, 0, 0);
    }
  }
  #pragma unroll
  for (int m = 0; m < 4; ++m)
    #pragma unroll
    for (int n = 0; n < 4; ++n)
      #pragma unroll
      for (int r = 0; r < 4; ++r){
        int row = m0 + wr*64 + m*16 + lg*4 + r;
        int col = n0 + wc*64 + n*16 + lr;
        out[(size_t)row * DOUT + col] = acc[m][n][r];   // fp32 output
      }
}

// ---------------- chunked scan ----------------
// mapping: tid -> ch (0..1023), b (0..7), ck (0..NCH-1)
__global__ void scanA_kernel(const u16* __restrict__ cb, const u16* __restrict__ vb,
                             const void* __restrict__ isin, const int* __restrict__ mode,
                             float* __restrict__ Cc, float* __restrict__ Vc)
{
  int tid = blockIdx.x * 256 + threadIdx.x;
  int ch = tid & 1023, b = (tid >> 10) & 7, ck = tid >> 13;
  int md = *mode;
  const unsigned char* ib = (const unsigned char*)isin;
  const int* ii = (const int*)isin;
  int t0 = b * T_ + ck * CL;
  float C = 1.f, V = 0.f;
  #pragma unroll 8
  for (int i = 0; i < CL; ++i){
    int t = t0 + i;
    size_t idx = (size_t)t * HCH + ch;
    float c = bf2f(cb[idx]);
    float v = bf2f(vb[idx]);
    int r = md ? (int)ib[t] : ii[t];
    if (r){ C = 0.f; V = v; } else { V = __fmaf_rn(c, V, v); C *= c; }
  }
  int o = ck * 8192 + b * 1024 + ch;
  Cc[o] = C; Vc[o] = V;
}

__global__ void scanB_kernel(const float* __restrict__ Cc, const float* __restrict__ Vc,
                             float* __restrict__ hin)
{
  int idx = blockIdx.x * 256 + threadIdx.x;   // 0..8191 = b*1024+ch
  float h = 0.f;                              // h_{-1} = 0
  #pragma unroll 8
  for (int ck = 0; ck < NCH; ++ck){
    int o = ck * 8192 + idx;
    hin[o] = h;
    h = __fmaf_rn(Cc[o], h, Vc[o]);
  }
}

__global__ void scanC_kernel(const u16* __restrict__ cb, const u16* __restrict__ vb,
                             const void* __restrict__ isin, const int* __restrict__ mode,
                             const float* __restrict__ hin,
                             u16* __restrict__ hbf, float* __restrict__ hn)
{
  int tid = blockIdx.x * 256 + threadIdx.x;
  int ch = tid & 1023, b = (tid >> 10) & 7, ck = tid >> 13;
  int md = *mode;
  const unsigned char* ib = (const unsigned char*)isin;
  const int* ii = (const int*)isin;
  int t0 = b * T_ + ck * CL;
  float h = hin[ck * 8192 + b * 1024 + ch];
  #pragma unroll 8
  for (int i = 0; i < CL; ++i){
    int t = t0 + i;
    size_t idx = (size_t)t * HCH + ch;
    float c = bf2f(cb[idx]);
    float v = bf2f(vb[idx]);
    int r = md ? (int)ib[t] : ii[t];
    h = r ? v : __fmaf_rn(c, h, v);
    hbf[idx] = f2bf(h);
  }
  if (ck == NCH - 1) hn[b * 1024 + ch] = h;   // h_n = h[:, -1], fp32
}

// ---------------- launcher ----------------
extern "C" void kernel_launch(void* const* d_in, const int* in_sizes, int n_in,
                              void* d_out, int out_size, void* d_ws, size_t ws_size,
                              hipStream_t stream)
{
  const float* x    = (const float*)d_in[0];
  const void*  isin = d_in[1];
  const float* Whg  = (const float*)d_in[2];
  const float* Wout = (const float*)d_in[3];
  float* out = (float*)d_out;   // fp32 output (out_npz size ⇒ reference returns fp32)

  char* ws = (char*)d_ws;
  size_t off = 0;
  auto alloc = [&](size_t bytes) -> char* {
    char* p = ws + off;
    off += (bytes + 255) & ~(size_t)255;
    return p;
  };
  u16*   xbf   = (u16*)  alloc((size_t)M_ * DIN * 2);       // 67 MB
  u16*   WThg  = (u16*)  alloc((size_t)2 * HCH * DIN * 2);  // 4 MB
  u16*   WTout = (u16*)  alloc((size_t)DOUT * HCH * 2);     // 2 MB
  u16*   cbuf  = (u16*)  alloc((size_t)M_ * HCH * 2);       // 67 MB
  u16*   vbuf  = (u16*)  alloc((size_t)M_ * HCH * 2);       // 67 MB
  u16*   hbf   = (u16*)  alloc((size_t)M_ * HCH * 2);       // 67 MB
  float* Cc    = (float*)alloc((size_t)NCH * 8192 * 4);     // 2 MB
  float* Vc    = (float*)alloc((size_t)NCH * 8192 * 4);     // 2 MB
  float* hin   = (float*)alloc((size_t)NCH * 8192 * 4);     // 2 MB
  int*   mode  = (int*)  alloc(256);
  (void)ws_size; (void)in_sizes; (void)n_in; (void)out_size;

  detect_kernel<<<1, 256, 0, stream>>>((const unsigned char*)isin, mode);
  cvt_bf16_kernel<<<(M_*DIN/4 + 255)/256, 256, 0, stream>>>(x, xbf, M_*DIN/4);
  transpose_cvt_kernel<<<dim3(2*HCH/32, DIN/32), 256, 0, stream>>>(Whg, WThg, DIN, 2*HCH);
  transpose_cvt_kernel<<<dim3(DOUT/32, HCH/32), 256, 0, stream>>>(Wout, WTout, HCH, DOUT);
  gemm1_kernel<<<dim3(M_/128, HCH/128), 256, 0, stream>>>(xbf, WThg, cbuf, vbuf);
  scanA_kernel<<<(8192*NCH)/256, 256, 0, stream>>>(cbuf, vbuf, isin, mode, Cc, Vc);
  scanB_kernel<<<8192/256, 256, 0, stream>>>(Cc, Vc, hin);
  scanC_kernel<<<(8192*NCH)/256, 256, 0, stream>>>(cbuf, vbuf, isin, mode, hin, hbf,
                                                   out + (size_t)M_ * DOUT);
  gemm2_kernel<<<dim3(M_/128, DOUT/128), 256, 0, stream>>>(hbf, WTout, out);
}

// Round 3
// 604.784 us; speedup vs baseline: 1.0445x; 1.0445x over previous
//
#include <hip/hip_runtime.h>
#include <stdint.h>

#define B_    8
#define T_    4096
#define DIN   1024
#define HCH   1024
#define DOUT  1024
#define M_    (B_*T_)      // 32768 rows
#define CL    64           // scan chunk length
#define NCH   (T_/CL)      // 64 chunks

typedef unsigned short u16;
typedef unsigned int   u32;
typedef __attribute__((ext_vector_type(8))) __bf16 bf16x8;
typedef __attribute__((ext_vector_type(4))) float  f32x4;

static __device__ __forceinline__ u16 f2bf(float f){
  unsigned u = __builtin_bit_cast(unsigned, f);
  return (u16)((u + 0x7FFFu + ((u >> 16) & 1u)) >> 16);   // RNE
}
static __device__ __forceinline__ float bf2f(u16 h){
  return __builtin_bit_cast(float, ((unsigned)h) << 16);
}

#define GLOAD_LDS16(gp, lp) __builtin_amdgcn_global_load_lds( \
    (__attribute__((address_space(1))) void*)(gp),            \
    (__attribute__((address_space(3))) void*)(lp), 16, 0, 0)

#define BARRIER() do { __builtin_amdgcn_sched_barrier(0); \
                       __builtin_amdgcn_s_barrier();      \
                       __builtin_amdgcn_sched_barrier(0); } while(0)

// ---------------- conversions ----------------
__global__ void cvt_bf16_kernel(const float* __restrict__ in, u16* __restrict__ out, int n4){
  int i = blockIdx.x * blockDim.x + threadIdx.x;
  if (i >= n4) return;
  float4 v = ((const float4*)in)[i];
  ushort4 o;
  o.x = f2bf(v.x); o.y = f2bf(v.y); o.z = f2bf(v.z); o.w = f2bf(v.w);
  ((ushort4*)out)[i] = o;
}

// in: R x C fp32 row-major  ->  out: C x R bf16 row-major
__global__ void transpose_cvt_kernel(const float* __restrict__ in, u16* __restrict__ out,
                                     int R, int C){
  __shared__ float tile[32][33];
  int tx = threadIdx.x & 31, ty = threadIdx.x >> 5;   // 32 x 8
  int c0 = blockIdx.x * 32, r0 = blockIdx.y * 32;
  #pragma unroll
  for (int j = 0; j < 4; ++j)
    tile[ty + j*8][tx] = in[(size_t)(r0 + ty + j*8) * C + c0 + tx];
  __syncthreads();
  #pragma unroll
  for (int j = 0; j < 4; ++j)
    out[(size_t)(c0 + ty + j*8) * R + r0 + tx] = f2bf(tile[tx][ty + j*8]);
}

// Detect is_init storage: 1 => byte-per-flag (bool/int8), 0 => int32 values 0/1.
__global__ void detect_kernel(const u32* __restrict__ p, int* __restrict__ flag){
  __shared__ int s;
  if (threadIdx.x == 0) s = 0;
  __syncthreads();
  int f = 0;
  for (int i = threadIdx.x; i < (B_*T_)/4; i += 1024)
    if (p[i] & 0xFFFFFF00u) f = 1;
  if (f) atomicOr(&s, 1);
  __syncthreads();
  if (threadIdx.x == 0) *flag = s;
}

// ---------------- 8-phase 256^2 GEMM (K=1024, M=32768) ----------------
// A: [M][1024] bf16.  BT: [NOUT][1024] bf16 (B^T layout).  out: [M][NOUT].
// 512 threads = 8 waves (2 Mx 4 N). Per-wave output: 4 sub-blocks 64x32:
// rows {wm*64..+64} in each A-half, cols {wn*32..+32} in each B-half.
// LDS swizzle: 16B-granule g stored at g ^ (row&7); applied on BOTH the
// global_load_lds source address and the ds_read address (rule 21).
template<bool BF16OUT, int NOUT>
__global__ __launch_bounds__(512, 2) void gemm8p_kernel(
    const u16* __restrict__ A, const u16* __restrict__ BT, void* __restrict__ outv)
{
  __shared__ u16 As[2][16384];   // [buf][256 rows][64 cols]
  __shared__ u16 Bs[2][16384];

  const int tid = threadIdx.x, lane = tid & 63, w = tid >> 6;
  const int wm = w >> 2, wn = w & 3;
  const int lr = lane & 15, lg = lane >> 4;
  const int l8 = lane >> 3, l7 = lane & 7;
  const int sgcol = (l7 ^ l8) * 8;             // pre-swizzled source granule

  // XCD-aware swizzle (nwg % 8 == 0 for both instantiations)
  const int nwg = gridDim.x;
  const int wg  = ((int)blockIdx.x & 7) * (nwg >> 3) + ((int)blockIdx.x >> 3);
  const int mb  = wg & 127;                    // M/256 = 128 blocks
  const int nb  = wg >> 7;
  const int m0  = mb * 256, n0 = nb * 256;

  const u16* __restrict__ Ab = A  + (size_t)m0 * 1024;
  const u16* __restrict__ Bb = BT + (size_t)n0 * 1024;

  // stage one half-tile (128 rows x 64 cols) of tile tt into S[buf][half]
  auto stage = [&](u16 (*S)[16384], int buf, int half, int tt, const u16* __restrict__ Gb){
    #pragma unroll
    for (int i = 0; i < 2; ++i){
      int wi = w*2 + i;                        // 1KB window 0..15 within half
      GLOAD_LDS16(Gb + (size_t)(half*128 + wi*8 + l8) * 1024 + tt*64 + sgcol,
                  &S[buf][half*8192 + wi*512]);
    }
  };

  bf16x8 af[4][2], b0[2][2], b1[2][2];
  f32x4 acc[2][2][4][2];
  #pragma unroll
  for (int a = 0; a < 2; ++a)
    #pragma unroll
    for (int b = 0; b < 2; ++b)
      #pragma unroll
      for (int m = 0; m < 4; ++m)
        #pragma unroll
        for (int n = 0; n < 2; ++n)
          acc[a][b][m][n] = (f32x4){0.f,0.f,0.f,0.f};

  auto ldA = [&](int buf, int mh){
    #pragma unroll
    for (int m = 0; m < 4; ++m)
      #pragma unroll
      for (int ks = 0; ks < 2; ++ks){
        int R = mh*128 + wm*64 + m*16 + lr;
        int g = (ks*4 + lg) ^ (lr & 7);
        af[m][ks] = *(const bf16x8*)&As[buf][R*64 + g*8];
      }
  };
  auto ldB = [&](bf16x8 (&bv)[2][2], int buf, int nh){
    #pragma unroll
    for (int n = 0; n < 2; ++n)
      #pragma unroll
      for (int ks = 0; ks < 2; ++ks){
        int R = nh*128 + wn*32 + n*16 + lr;
        int g = (ks*4 + lg) ^ (lr & 7);
        bv[n][ks] = *(const bf16x8*)&Bs[buf][R*64 + g*8];
      }
  };
  auto mmaQ = [&](f32x4 (&ac)[4][2], bf16x8 (&bv)[2][2]){
    __builtin_amdgcn_s_setprio(1);
    #pragma unroll
    for (int m = 0; m < 4; ++m)
      #pragma unroll
      for (int n = 0; n < 2; ++n)
        #pragma unroll
        for (int ks = 0; ks < 2; ++ks)
          ac[m][n] = __builtin_amdgcn_mfma_f32_16x16x32_bf16(af[m][ks], bv[n][ks], ac[m][n], 0, 0, 0);
    __builtin_amdgcn_s_setprio(0);
  };

  // ---- prologue: tile0 all 4 halves, tile1 first 3 halves ----
  stage(As, 0, 0, 0, Ab);   // t0.Ah0
  stage(Bs, 0, 0, 0, Bb);   // t0.Bh0
  stage(Bs, 0, 1, 0, Bb);   // t0.Bh1
  stage(As, 0, 1, 0, Ab);   // t0.Ah1
  stage(As, 1, 0, 1, Ab);   // t1.Ah0
  stage(Bs, 1, 0, 1, Bb);   // t1.Bh0
  stage(Bs, 1, 1, 1, Bb);   // t1.Bh1
  asm volatile("s_waitcnt vmcnt(6)" ::: "memory");   // tile0 fully landed
  BARRIER();

  // ---- main loop: 16 K-tiles, 4 phases each ----
  for (int t = 0; t < 16; ++t){
    int cur = t & 1;
    // P1 — quadrant (mh0, nh0); stage (t+1).Ah1
    ldA(cur, 0);
    ldB(b0, cur, 0);
    if (t+1 < 16) stage(As, cur^1, 1, t+1, Ab);
    BARRIER();
    mmaQ(acc[0][0], b0);
    BARRIER();
    // P2 — quadrant (mh0, nh1); stage (t+2).Ah0
    ldB(b1, cur, 1);
    if (t+2 < 16) stage(As, cur, 0, t+2, Ab);
    BARRIER();
    mmaQ(acc[0][1], b1);
    BARRIER();
    // P3 — quadrant (mh1, nh1); stage (t+2).Bh0
    ldA(cur, 1);
    if (t+2 < 16) stage(Bs, cur, 0, t+2, Bb);
    BARRIER();
    mmaQ(acc[1][1], b1);
    BARRIER();
    // P4 — quadrant (mh1, nh0); stage (t+2).Bh1; counted vmcnt
    if (t+2 < 16) stage(Bs, cur, 1, t+2, Bb);
    if (t < 14)       { asm volatile("s_waitcnt vmcnt(6)" ::: "memory"); }
    else if (t == 14) { asm volatile("s_waitcnt vmcnt(0)" ::: "memory"); }
    BARRIER();
    mmaQ(acc[1][0], b0);
    BARRIER();
  }

  // ---- epilogue ----
  #pragma unroll
  for (int mh = 0; mh < 2; ++mh)
    #pragma unroll
    for (int nh = 0; nh < 2; ++nh)
      #pragma unroll
      for (int m = 0; m < 4; ++m)
        #pragma unroll
        for (int n = 0; n < 2; ++n)
          #pragma unroll
          for (int r = 0; r < 4; ++r){
            int row = m0 + mh*128 + wm*64 + m*16 + lg*4 + r;
            int col = n0 + nh*128 + wn*32 + n*16 + lr;
            float v = acc[mh][nh][m][n][r];
            if (BF16OUT) ((u16*)outv)[(size_t)row * NOUT + col] = f2bf(v);
            else       ((float*)outv)[(size_t)row * NOUT + col] = v;
          }
}

// ---------------- fused elementwise helpers ----------------
// c = sigmoid(-gate), v = sigmoid(gate) * g(hidden); z = 1 - c.
static __device__ __forceinline__ void cv_from_hg(float hv, float gv, float& c, float& v){
  c = 1.f / (1.f + __expf(gv));
  float z = 1.f - c;
  float g = (hv >= 0.f) ? (hv + 0.5f) : (1.f / (1.f + __expf(-hv)));
  v = z * g;
}

// ---------------- chunked scan (pair-of-channels per thread) ----------------
__global__ void scanA_kernel(const u16* __restrict__ hg,
                             const void* __restrict__ isin, const int* __restrict__ mode,
                             float* __restrict__ Cc, float* __restrict__ Vc)
{
  int tid = blockIdx.x * 256 + threadIdx.x;        // 0..262143
  int chp = tid & 511, b = (tid >> 9) & 7, ck = tid >> 12;
  int ch0 = chp * 2;
  int md = *mode;
  const unsigned char* ib = (const unsigned char*)isin;
  const int* ii = (const int*)isin;
  int t0 = b * T_ + ck * CL;
  float C0 = 1.f, V0 = 0.f, C1 = 1.f, V1 = 0.f;
  #pragma unroll 4
  for (int i = 0; i < CL; ++i){
    int t = t0 + i;
    const u16* rowp = hg + (size_t)t * 2048;
    u32 h2 = *(const u32*)(rowp + ch0);
    u32 g2 = *(const u32*)(rowp + 1024 + ch0);
    float c0, v0, c1, v1;
    cv_from_hg(bf2f((u16)h2), bf2f((u16)(h2 >> 16)) * 0.f + bf2f((u16)(g2 & 0xFFFF)) * 0.f + bf2f((u16)h2), 0.f ? c0 : c0, v0); // placeholder avoided below
    // (explicit to keep codegen clean:)
    {
      float hv0 = bf2f((u16)(h2 & 0xFFFF)), hv1 = bf2f((u16)(h2 >> 16));
      float gv0 = bf2f((u16)(g2 & 0xFFFF)), gv1 = bf2f((u16)(g2 >> 16));
      cv_from_hg(hv0, gv0, c0, v0);
      cv_from_hg(hv1, gv1, c1, v1);
    }
    int r = md ? (int)ib[t] : ii[t];
    if (r){ C0 = 0.f; V0 = v0; C1 = 0.f; V1 = v1; }
    else  { V0 = __fmaf_rn(c0, V0, v0); C0 *= c0;
            V1 = __fmaf_rn(c1, V1, v1); C1 *= c1; }
  }
  int o = ck * 8192 + b * 1024 + ch0;
  *(float2*)&Cc[o] = make_float2(C0, C1);
  *(float2*)&Vc[o] = make_float2(V0, V1);
}

__global__ void scanB_kernel(const float* __restrict__ Cc, const float* __restrict__ Vc,
                             float* __restrict__ hin)
{
  int idx = blockIdx.x * 256 + threadIdx.x;   // 0..8191 = b*1024+ch
  float h = 0.f;                              // h_{-1} = 0
  #pragma unroll 8
  for (int ck = 0; ck < NCH; ++ck){
    int o = ck * 8192 + idx;
    hin[o] = h;
    h = __fmaf_rn(Cc[o], h, Vc[o]);
  }
}

__global__ void scanC_kernel(const u16* __restrict__ hg,
                             const void* __restrict__ isin, const int* __restrict__ mode,
                             const float* __restrict__ hin,
                             u16* __restrict__ hbf, float* __restrict__ hn)
{
  int tid = blockIdx.x * 256 + threadIdx.x;
  int chp = tid & 511, b = (tid >> 9) & 7, ck = tid >> 12;
  int ch0 = chp * 2;
  int md = *mode;
  const unsigned char* ib = (const unsigned char*)isin;
  const int* ii = (const int*)isin;
  int t0 = b * T_ + ck * CL;
  int o = ck * 8192 + b * 1024 + ch0;
  float h0 = hin[o], h1 = hin[o + 1];
  #pragma unroll 4
  for (int i = 0; i < CL; ++i){
    int t = t0 + i;
    const u16* rowp = hg + (size_t)t * 2048;
    u32 h2 = *(const u32*)(rowp + ch0);
    u32 g2 = *(const u32*)(rowp + 1024 + ch0);
    float hv0 = bf2f((u16)(h2 & 0xFFFF)), hv1 = bf2f((u16)(h2 >> 16));
    float gv0 = bf2f((u16)(g2 & 0xFFFF)), gv1 = bf2f((u16)(g2 >> 16));
    float c0, v0, c1, v1;
    cv_from_hg(hv0, gv0, c0, v0);
    cv_from_hg(hv1, gv1, c1, v1);
    int r = md ? (int)ib[t] : ii[t];
    h0 = r ? v0 : __fmaf_rn(c0, h0, v0);
    h1 = r ? v1 : __fmaf_rn(c1, h1, v1);
    *(u32*)&hbf[(size_t)t * HCH + ch0] = (u32)f2bf(h0) | ((u32)f2bf(h1) << 16);
  }
  if (ck == NCH - 1){ hn[b * 1024 + ch0] = h0; hn[b * 1024 + ch0 + 1] = h1; }
}

// ---------------- launcher ----------------
extern "C" void kernel_launch(void* const* d_in, const int* in_sizes, int n_in,
                              void* d_out, int out_size, void* d_ws, size_t ws_size,
                              hipStream_t stream)
{
  const float* x    = (const float*)d_in[0];
  const void*  isin = d_in[1];
  const float* Whg  = (const float*)d_in[2];
  const float* Wout = (const float*)d_in[3];
  float* out = (float*)d_out;

  char* ws = (char*)d_ws;
  size_t off = 0;
  auto alloc = [&](size_t bytes) -> char* {
    char* p = ws + off;
    off += (bytes + 255) & ~(size_t)255;
    return p;
  };
  u16*   xbf   = (u16*)  alloc((size_t)M_ * DIN * 2);        // 67 MB
  u16*   WThg  = (u16*)  alloc((size_t)2 * HCH * DIN * 2);   // 4 MB
  u16*   WTout = (u16*)  alloc((size_t)DOUT * HCH * 2);      // 2 MB
  u16*   hg    = (u16*)  alloc((size_t)M_ * 2 * HCH * 2);    // 134 MB
  u16*   hbf   = (u16*)  alloc((size_t)M_ * HCH * 2);        // 67 MB
  float* Cc    = (float*)alloc((size_t)NCH * 8192 * 4);      // 2 MB
  float* Vc    = (float*)alloc((size_t)NCH * 8192 * 4);      // 2 MB
  float* hin   = (float*)alloc((size_t)NCH * 8192 * 4);      // 2 MB
  int*   mode  = (int*)  alloc(256);
  (void)ws_size; (void)in_sizes; (void)n_in; (void)out_size;

  detect_kernel<<<1, 1024, 0, stream>>>((const u32*)isin, mode);
  cvt_bf16_kernel<<<(M_*DIN/4 + 255)/256, 256, 0, stream>>>(x, xbf, M_*DIN/4);
  transpose_cvt_kernel<<<dim3(2*HCH/32, DIN/32), 256, 0, stream>>>(Whg, WThg, DIN, 2*HCH);
  transpose_cvt_kernel<<<dim3(DOUT/32, HCH/32), 256, 0, stream>>>(Wout, WTout, HCH, DOUT);
  gemm8p_kernel<true, 2048><<<1024, 512, 0, stream>>>(xbf, WThg, hg);
  scanA_kernel<<<(8192*NCH/2)/256, 256, 0, stream>>>(hg, isin, mode, Cc, Vc);
  scanB_kernel<<<8192/256, 256, 0, stream>>>(Cc, Vc, hin);
  scanC_kernel<<<(8192*NCH/2)/256, 256, 0, stream>>>(hg, isin, mode, hin, hbf,
                                                     out + (size_t)M_ * DOUT);
  gemm8p_kernel<false, 1024><<<512, 512, 0, stream>>>(hbf, WTout, out);
}